// Round 1
// baseline (2284.817 us; speedup 1.0000x reference)
//
#include <hip/hip_runtime.h>
#include <hip/hip_bf16.h>
#include <math.h>

#define TE 32
#define XS 264          // x tile stride (shorts): 256 hE cols + 8 pad
#define HS 264          // hidden tile stride (shorts)
#define NTILES 18750    // 600000 / TE

typedef __attribute__((ext_vector_type(8))) short bf16x8;
typedef __attribute__((ext_vector_type(4))) float f32x4;

__device__ __forceinline__ unsigned short f2b(float f) {
    unsigned int x = __float_as_uint(f);
    unsigned int r = x + 0x7fffu + ((x >> 16) & 1u);   // RTNE
    return (unsigned short)(r >> 16);
}
__device__ __forceinline__ float b2f(unsigned short u) {
    return __uint_as_float(((unsigned int)u) << 16);
}
// Branchless erf-gelu (Abramowitz-Stegun 7.1.26, |erf err| <= 1.5e-7).
__device__ __forceinline__ float gelu_fast(float v) {
    float x = fabsf(v) * 0.70710678118654752f;
    float t = __builtin_amdgcn_rcpf(1.0f + 0.3275911f * x);
    float p = ((((1.061405429f * t - 1.453152027f) * t + 1.421413741f) * t
                - 0.284496736f) * t + 0.254829592f) * t;
    float e = __expf(-x * x);
    float erfp = 1.0f - p * e;                 // erf(|v|/sqrt2) >= 0
    return 0.5f * v * (1.0f + copysignf(erfp, v));
}

// ---------------- weight prep: fp32 -> bf16, Wb3 pad, Wo transpose ----------------
// wbf layout (shorts): Wb1[:,128:384] 32768 | Wb2 16384 | Wv1 32768 | Wv2 16384
//                      | Wv3 16384 | Wb3 padded 16x128 = 2048   (total 116736)
__global__ void __launch_bounds__(256)
k_pre(const float* __restrict__ Wb1, const float* __restrict__ Wb2,
      const float* __restrict__ Wv1, const float* __restrict__ Wv2,
      const float* __restrict__ Wv3, const float* __restrict__ Wb3,
      const float* __restrict__ Wo,
      unsigned short* __restrict__ wbf, float* __restrict__ woT) {
    int t = blockIdx.x * 256 + threadIdx.x;
    if (t < 32768) { int f = t >> 8, k = t & 255; wbf[t] = f2b(Wb1[f * 384 + 128 + k]); }
    else if (t < 49152)  wbf[t] = f2b(Wb2[t - 32768]);
    else if (t < 81920)  wbf[t] = f2b(Wv1[t - 49152]);
    else if (t < 98304)  wbf[t] = f2b(Wv2[t - 81920]);
    else if (t < 114688) wbf[t] = f2b(Wv3[t - 98304]);
    else if (t < 116736) {
        int i = t - 114688; int r = i >> 7, k = i & 127;
        wbf[t] = (r < 4) ? f2b(Wb3[r * 128 + k]) : (unsigned short)0;
    } else if (t < 133120) {
        int i = t - 116736; int j = i >> 7, k = i & 127;
        woT[k * 128 + j] = Wo[j * 128 + k];
    }
}

// ---------------- per-node bias-L1 partial: P = h_V @ Wb1[:, :128]^T + bb1 (bf16) ----------------
__global__ void __launch_bounds__(256)
k_pnode(const float* __restrict__ hV, const float* __restrict__ Wb1,
        const float* __restrict__ bb1, unsigned short* __restrict__ Pbf) {
    const int t = threadIdx.x;
    const int lane = t & 63;
    const int node = blockIdx.x * 4 + (t >> 6);
    const int f0 = lane * 2;
    const float* hv = hV + (size_t)node * 128;
    const float* w0 = Wb1 + (size_t)f0 * 384;
    const float* w1 = w0 + 384;
    float a0 = 0.f, a1 = 0.f;
    #pragma unroll 4
    for (int kk = 0; kk < 32; ++kk) {
        float4 h  = *(const float4*)(hv + kk * 4);
        float4 x0 = *(const float4*)(w0 + kk * 4);
        float4 x1 = *(const float4*)(w1 + kk * 4);
        a0 += h.x * x0.x + h.y * x0.y + h.z * x0.z + h.w * x0.w;
        a1 += h.x * x1.x + h.y * x1.y + h.z * x1.z + h.w * x1.w;
    }
    ushort2 p; p.x = f2b(a0 + bb1[f0]); p.y = f2b(a1 + bb1[f0 + 1]);
    *(ushort2*)&Pbf[(size_t)node * 128 + f0] = p;
}

// ---------------- CSR build ----------------
__global__ void __launch_bounds__(256)
k_hist(const int* __restrict__ center, int* __restrict__ counts) {
    int t = blockIdx.x * 256 + threadIdx.x;
    if (t < 600000) atomicAdd(&counts[center[t]], 1);
}

// single-block shuffle scan: cursor = exclusive prefix of counts (~5us vs ~50us)
__global__ void __launch_bounds__(1024)
k_scan(const int* __restrict__ counts, int* __restrict__ cursor, int n) {
    __shared__ int wtot[16];
    const int t = threadIdx.x, lane = t & 63, w = t >> 6;
    const int CH = 20;                       // 1024*20 >= 20000
    const int base = t * CH;
    int loc[CH]; int s = 0;
    #pragma unroll
    for (int i = 0; i < CH; ++i) {
        int idx = base + i;
        int v = (idx < n) ? counts[idx] : 0;
        loc[i] = s; s += v;
    }
    int inc = s;
    for (int o = 1; o < 64; o <<= 1) { int u = __shfl_up(inc, o); if (lane >= o) inc += u; }
    if (lane == 63) wtot[w] = inc;
    __syncthreads();
    if (w == 0 && lane < 16) {
        int v = wtot[lane]; int p = v;
        for (int o = 1; o < 16; o <<= 1) { int u = __shfl_up(p, o); if (lane >= o) p += u; }
        wtot[lane] = p - v;                  // exclusive wave offset
    }
    __syncthreads();
    const int excl = wtot[w] + inc - s;
    #pragma unroll
    for (int i = 0; i < CH; ++i) {
        int idx = base + i;
        if (idx < n) cursor[idx] = excl + loc[i];
    }
}

__global__ void __launch_bounds__(256)
k_place(const int* __restrict__ center, int* __restrict__ cursor, int* __restrict__ eidx) {
    int t = blockIdx.x * 256 + threadIdx.x;
    if (t < 600000) {
        int p = atomicAdd(&cursor[center[t]], 1);
        eidx[p] = t;
    }
}

// ---------------- fused per-edge MLPs, edges processed in node-sorted (eidx) order ----------------
// prefetch next tile's (eidx -> hE rows, center) into registers; outputs contiguous.
#define PREFETCH(eg) { \
    int e0_ = eidx[(eg) + wave];      int e1_ = eidx[(eg) + wave + 8]; \
    int e2_ = eidx[(eg) + wave + 16]; int e3_ = eidx[(eg) + wave + 24]; \
    if (t < 32) pc = center[eidx[(eg) + t]]; \
    pre[0] = *(const float4*)(hE + (size_t)e0_ * 256 + kq4); \
    pre[1] = *(const float4*)(hE + (size_t)e1_ * 256 + kq4); \
    pre[2] = *(const float4*)(hE + (size_t)e2_ * 256 + kq4); \
    pre[3] = *(const float4*)(hE + (size_t)e3_ * 256 + kq4); }

#define STAGE() { \
    _Pragma("unroll") \
    for (int i_ = 0; i_ < 4; ++i_) { \
        ushort4 p_; p_.x = f2b(pre[i_].x); p_.y = f2b(pre[i_].y); \
        p_.z = f2b(pre[i_].z); p_.w = f2b(pre[i_].w); \
        *(ushort4*)&xs[(wave + i_ * 8) * XS + kq4] = p_; } \
    if (t < 32) cs[t] = pc; }

__global__ void __launch_bounds__(512, 6)
k_edge(const float* __restrict__ hE, const int* __restrict__ center,
       const int* __restrict__ eidx, const unsigned short* __restrict__ Pbf,
       const float* __restrict__ bv1, const float* __restrict__ bv2,
       const float* __restrict__ bv3, const float* __restrict__ bb2,
       const float* __restrict__ bb3, const unsigned short* __restrict__ wbf,
       unsigned short* __restrict__ Vbf, float* __restrict__ ew, float* __restrict__ denom)
{
    __shared__ unsigned short smem[25344];   // xs[32*264] + h1[32*264] + h2[32*264] = 50688 B
    __shared__ int cs[32];                   // center of each (permuted) edge row
    const int t = threadIdx.x;
    const int wave = t >> 6, lane = t & 63;
    const int c16 = lane & 15, q = lane >> 4;
    const int kq4 = (t & 63) * 4;

    unsigned short* xs = smem;               // [32][XS] bf16(h_E) rows in eidx order
    unsigned short* h1 = smem + 8448;        // [32][HS]
    unsigned short* h2 = smem + 16896;       // [32][HS]

    const unsigned short* Wb1bf = wbf;               // 128 x 256 (cols 128..383 of Wb1)
    const unsigned short* Wb2bf = wbf + 32768;
    const unsigned short* Wv1bf = wbf + 49152;
    const unsigned short* Wv2bf = wbf + 81920;
    const unsigned short* Wv3bf = wbf + 98304;
    const unsigned short* Wb3bf = wbf + 114688;      // 16 x 128 (rows 4..15 zero)

    float4 pre[4]; int pc = 0;
    PREFETCH(blockIdx.x * TE);               // prologue prefetch

    if (wave < 4) {
        // ================= bias path: features fb..fb+31 =================
        const int fb = wave * 32;
        bf16x8 wb1r[2][8], wb2r[2][4], wb3f[4];
        float bias2[2]; float bb3c = 0.f;
        #pragma unroll
        for (int nt = 0; nt < 2; ++nt) {
            const int fr = fb + nt * 16 + c16;
            #pragma unroll
            for (int ks = 0; ks < 8; ++ks)
                wb1r[nt][ks] = *(const bf16x8*)(Wb1bf + (size_t)fr * 256 + ks * 32 + q * 8);
            #pragma unroll
            for (int ks = 0; ks < 4; ++ks)
                wb2r[nt][ks] = *(const bf16x8*)(Wb2bf + (size_t)fr * 128 + ks * 32 + q * 8);
            bias2[nt] = bb2[fr];
        }
        if (wave == 0) {
            #pragma unroll
            for (int ks = 0; ks < 4; ++ks)
                wb3f[ks] = *(const bf16x8*)(Wb3bf + (size_t)c16 * 128 + ks * 32 + q * 8);
            bb3c = bb3[c16 & 3];
        }
        for (int tile = blockIdx.x; tile < NTILES; tile += gridDim.x) {
            const int eg0 = tile * TE;
            STAGE();
            int nxt = tile + gridDim.x;
            if (nxt < NTILES) PREFETCH(nxt * TE);
            __syncthreads();
            // ---- per-row gather of precomputed h_V partial (sorted centers -> cache-hot) ----
            float pva[2][2][4];
            #pragma unroll
            for (int m = 0; m < 2; ++m)
                #pragma unroll
                for (int r = 0; r < 4; ++r) {
                    int c = cs[m * 16 + q * 4 + r];
                    pva[m][0][r] = b2f(Pbf[(size_t)c * 128 + fb + c16]);
                    pva[m][1][r] = b2f(Pbf[(size_t)c * 128 + fb + 16 + c16]);
                }
            // ---- L1: h1b = gelu(hE @ Wb1[:,128:]^T + P[center]), K=256 ----
            #pragma unroll
            for (int m = 0; m < 2; ++m) {
                bf16x8 af[8];
                #pragma unroll
                for (int ks = 0; ks < 8; ++ks)
                    af[ks] = *(const bf16x8*)&xs[(m * 16 + c16) * XS + ks * 32 + q * 8];
                f32x4 a0 = {0.f,0.f,0.f,0.f}, a1 = {0.f,0.f,0.f,0.f};
                #pragma unroll
                for (int ks = 0; ks < 8; ++ks) {
                    a0 = __builtin_amdgcn_mfma_f32_16x16x32_bf16(af[ks], wb1r[0][ks], a0, 0, 0, 0);
                    a1 = __builtin_amdgcn_mfma_f32_16x16x32_bf16(af[ks], wb1r[1][ks], a1, 0, 0, 0);
                }
                #pragma unroll
                for (int r = 0; r < 4; ++r) {
                    int row = (m * 16 + q * 4 + r) * HS;
                    h1[row + fb + c16]      = f2b(gelu_fast(a0[r] + pva[m][0][r]));
                    h1[row + fb + 16 + c16] = f2b(gelu_fast(a1[r] + pva[m][1][r]));
                }
            }
            __syncthreads();
            // ---- L2: h2b = gelu(h1b @ Wb2^T + bb2), K=128 ----
            #pragma unroll
            for (int m = 0; m < 2; ++m) {
                bf16x8 ah[4];
                #pragma unroll
                for (int ks = 0; ks < 4; ++ks)
                    ah[ks] = *(const bf16x8*)&h1[(m * 16 + c16) * HS + ks * 32 + q * 8];
                f32x4 a0 = {0.f,0.f,0.f,0.f}, a1 = {0.f,0.f,0.f,0.f};
                #pragma unroll
                for (int ks = 0; ks < 4; ++ks) {
                    a0 = __builtin_amdgcn_mfma_f32_16x16x32_bf16(ah[ks], wb2r[0][ks], a0, 0, 0, 0);
                    a1 = __builtin_amdgcn_mfma_f32_16x16x32_bf16(ah[ks], wb2r[1][ks], a1, 0, 0, 0);
                }
                #pragma unroll
                for (int r = 0; r < 4; ++r) {
                    int row = (m * 16 + q * 4 + r) * HS;
                    h2[row + fb + c16]      = f2b(gelu_fast(a0[r] + bias2[0]));
                    h2[row + fb + 16 + c16] = f2b(gelu_fast(a1[r] + bias2[1]));
                }
            }
            __syncthreads();
            // ---- L3 (wave 0, MFMA): logits = h2b @ Wb3pad^T -> ew (contiguous), denom atomics ----
            if (wave == 0) {
                #pragma unroll
                for (int m = 0; m < 2; ++m) {
                    bf16x8 ah[4];
                    #pragma unroll
                    for (int ks = 0; ks < 4; ++ks)
                        ah[ks] = *(const bf16x8*)&h2[(m * 16 + c16) * HS + ks * 32 + q * 8];
                    f32x4 a = {0.f,0.f,0.f,0.f};
                    #pragma unroll
                    for (int ks = 0; ks < 4; ++ks)
                        a = __builtin_amdgcn_mfma_f32_16x16x32_bf16(ah[ks], wb3f[ks], a, 0, 0, 0);
                    if (c16 < 4) {
                        #pragma unroll
                        for (int r = 0; r < 4; ++r) {
                            int row = m * 16 + q * 4 + r;
                            float wv = (a[r] + bb3c) * 0.17677669529663689f;  // 1/sqrt(32)
                            float evx = __expf(wv);                 // |w| small: no max-sub
                            ew[(size_t)(eg0 + row) * 4 + c16] = evx;
                            atomicAdd(&denom[(size_t)cs[row] * 4 + c16], evx);
                        }
                    }
                }
            }
        }
    } else {
        // ================= value path: features fv..fv+31 =================
        const int fv = (wave - 4) * 32;
        bf16x8 wv1r[2][8], wv2r[2][4], wv3r[2][4];
        float b1[2], b2[2], b3[2];
        #pragma unroll
        for (int nt = 0; nt < 2; ++nt) {
            const int fr = fv + nt * 16 + c16;
            #pragma unroll
            for (int ks = 0; ks < 8; ++ks)
                wv1r[nt][ks] = *(const bf16x8*)(Wv1bf + (size_t)fr * 256 + ks * 32 + q * 8);
            #pragma unroll
            for (int ks = 0; ks < 4; ++ks) {
                wv2r[nt][ks] = *(const bf16x8*)(Wv2bf + (size_t)fr * 128 + ks * 32 + q * 8);
                wv3r[nt][ks] = *(const bf16x8*)(Wv3bf + (size_t)fr * 128 + ks * 32 + q * 8);
            }
            b1[nt] = bv1[fr]; b2[nt] = bv2[fr]; b3[nt] = bv3[fr];
        }
        for (int tile = blockIdx.x; tile < NTILES; tile += gridDim.x) {
            const int eg0 = tile * TE;
            STAGE();
            int nxt = tile + gridDim.x;
            if (nxt < NTILES) PREFETCH(nxt * TE);
            __syncthreads();
            // ---- L1: v1 = gelu(h_E @ Wv1^T + bv1), K=256 ----
            #pragma unroll
            for (int m = 0; m < 2; ++m) {
                bf16x8 af[8];
                #pragma unroll
                for (int ks = 0; ks < 8; ++ks)
                    af[ks] = *(const bf16x8*)&xs[(m * 16 + c16) * XS + ks * 32 + q * 8];
                f32x4 a0 = {0.f,0.f,0.f,0.f}, a1 = {0.f,0.f,0.f,0.f};
                #pragma unroll
                for (int ks = 0; ks < 8; ++ks) {
                    a0 = __builtin_amdgcn_mfma_f32_16x16x32_bf16(af[ks], wv1r[0][ks], a0, 0, 0, 0);
                    a1 = __builtin_amdgcn_mfma_f32_16x16x32_bf16(af[ks], wv1r[1][ks], a1, 0, 0, 0);
                }
                #pragma unroll
                for (int r = 0; r < 4; ++r) {
                    int row = (m * 16 + q * 4 + r) * HS;
                    h1[row + 128 + fv + c16]      = f2b(gelu_fast(a0[r] + b1[0]));
                    h1[row + 128 + fv + 16 + c16] = f2b(gelu_fast(a1[r] + b1[1]));
                }
            }
            __syncthreads();
            // ---- L2: v2 = gelu(v1 @ Wv2^T + bv2), K=128 ----
            #pragma unroll
            for (int m = 0; m < 2; ++m) {
                bf16x8 ah[4];
                #pragma unroll
                for (int ks = 0; ks < 4; ++ks)
                    ah[ks] = *(const bf16x8*)&h1[(m * 16 + c16) * HS + 128 + ks * 32 + q * 8];
                f32x4 a0 = {0.f,0.f,0.f,0.f}, a1 = {0.f,0.f,0.f,0.f};
                #pragma unroll
                for (int ks = 0; ks < 4; ++ks) {
                    a0 = __builtin_amdgcn_mfma_f32_16x16x32_bf16(ah[ks], wv2r[0][ks], a0, 0, 0, 0);
                    a1 = __builtin_amdgcn_mfma_f32_16x16x32_bf16(ah[ks], wv2r[1][ks], a1, 0, 0, 0);
                }
                #pragma unroll
                for (int r = 0; r < 4; ++r) {
                    int row = (m * 16 + q * 4 + r) * HS;
                    h2[row + 128 + fv + c16]      = f2b(gelu_fast(a0[r] + b2[0]));
                    h2[row + 128 + fv + 16 + c16] = f2b(gelu_fast(a1[r] + b2[1]));
                }
            }
            __syncthreads();
            // ---- L3: V = v2 @ Wv3^T + bv3 -> Vbf at CONTIGUOUS (sorted) position ----
            #pragma unroll
            for (int m = 0; m < 2; ++m) {
                bf16x8 av[4];
                #pragma unroll
                for (int ks = 0; ks < 4; ++ks)
                    av[ks] = *(const bf16x8*)&h2[(m * 16 + c16) * HS + 128 + ks * 32 + q * 8];
                f32x4 a0 = {0.f,0.f,0.f,0.f}, a1 = {0.f,0.f,0.f,0.f};
                #pragma unroll
                for (int ks = 0; ks < 4; ++ks) {
                    a0 = __builtin_amdgcn_mfma_f32_16x16x32_bf16(av[ks], wv3r[0][ks], a0, 0, 0, 0);
                    a1 = __builtin_amdgcn_mfma_f32_16x16x32_bf16(av[ks], wv3r[1][ks], a1, 0, 0, 0);
                }
                #pragma unroll
                for (int r = 0; r < 4; ++r) {
                    size_t row = (size_t)(eg0 + m * 16 + q * 4 + r) * 128;
                    Vbf[row + fv + c16]      = f2b(a0[r] + b3[0]);
                    Vbf[row + fv + 16 + c16] = f2b(a1[r] + b3[1]);
                }
            }
        }
    }
}

// -------- gather+output: Vbf/ew now CONTIGUOUS per node -> pure streaming --------
__global__ void __launch_bounds__(256)
k_agg_out(const unsigned short* __restrict__ Vbf, const float* __restrict__ ew,
          const float* __restrict__ denom, const int* __restrict__ cursor,
          const int* __restrict__ counts, const float* __restrict__ woT,
          float* __restrict__ out)
{
    __shared__ float aggs[4][128];
    const int t = threadIdx.x;
    const int ln = t >> 6;
    const int node = blockIdx.x * 4 + ln;
    const int lane = t & 63;
    const int j = lane * 2, head = j >> 5;
    {
        int deg = counts[node];
        int off = cursor[node] - deg;        // cursor(after place) = start + deg
        float den = denom[(size_t)node * 4 + head];
        float dinv = (den != 0.f) ? (1.f / den) : 0.f;
        const unsigned short* vp = Vbf + (size_t)off * 128 + j;
        const float* ep = ew + (size_t)off * 4 + head;
        float a0 = 0.f, a1 = 0.f;
        for (int i = 0; i < deg; ++i) {
            float at = ep[(size_t)i * 4] * dinv;
            ushort2 v = *(const ushort2*)(vp + (size_t)i * 128);
            a0 += at * b2f(v.x);
            a1 += at * b2f(v.y);
        }
        aggs[ln][j]     = a0;
        aggs[ln][j + 1] = a1;
    }
    __syncthreads();
    {
        const int c = t & 127, nh = t >> 7;
        float o0 = 0.f, o1 = 0.f;
        for (int k = 0; k < 128; ++k) {
            float w = woT[k * 128 + c];
            o0 += w * aggs[nh][k];
            o1 += w * aggs[nh + 2][k];
        }
        out[(size_t)(blockIdx.x * 4 + nh) * 128 + c]     = o0;
        out[(size_t)(blockIdx.x * 4 + nh + 2) * 128 + c] = o1;
    }
}

extern "C" void kernel_launch(void* const* d_in, const int* in_sizes, int n_in,
                              void* d_out, int out_size, void* d_ws, size_t ws_size,
                              hipStream_t stream) {
    const float* hV  = (const float*)d_in[0];
    const float* hE  = (const float*)d_in[1];
    const float* Wv1 = (const float*)d_in[2];
    const float* bv1 = (const float*)d_in[3];
    const float* Wv2 = (const float*)d_in[4];
    const float* bv2 = (const float*)d_in[5];
    const float* Wv3 = (const float*)d_in[6];
    const float* bv3 = (const float*)d_in[7];
    const float* Wb1 = (const float*)d_in[8];
    const float* bb1 = (const float*)d_in[9];
    const float* Wb2 = (const float*)d_in[10];
    const float* bb2 = (const float*)d_in[11];
    const float* Wb3 = (const float*)d_in[12];
    const float* bb3 = (const float*)d_in[13];
    const float* Wo  = (const float*)d_in[14];
    const int* center = (const int*)d_in[15];
    float* out = (float*)d_out;

    // ---- workspace layout (peak 171,499,008 B < Round-1-proven 174 MB) ----
    char* ws = (char*)d_ws;
    unsigned short* wbf = (unsigned short*)(ws + 0);          // 116736 bf16 (233472 B)
    float* woT     = (float*)(ws + 233472);                   // 16384 f32   (65536 B)
    unsigned short* Pbf = (unsigned short*)(ws + 299008);     // 2.56M bf16  (5120000 B)
    float* denom   = (float*)(ws + 5419008);                  // 80000 f32   (320000 B)
    int*   counts  = (int*)  (ws + 5739008);                  // 20000       (80000 B)
    int*   cursor  = (int*)  (ws + 5819008);                  // 20000       (80000 B)
    int*   eidx    = (int*)  (ws + 5899008);                  // 600000      (2400000 B)
    float* ew      = (float*)(ws + 8299008);                  // 2400000 f32 (9600000 B)
    unsigned short* Vbf = (unsigned short*)(ws + 17899008);   // 76800000 bf16 (153600000 B)

    hipMemsetAsync(ws + 5419008, 0, 400000, stream);          // zero denom + counts
    k_pre  <<<520, 256, 0, stream>>>(Wb1, Wb2, Wv1, Wv2, Wv3, Wb3, Wo, wbf, woT);
    k_pnode<<<5000, 256, 0, stream>>>(hV, Wb1, bb1, Pbf);
    k_hist <<<2344, 256, 0, stream>>>(center, counts);
    k_scan <<<1, 1024, 0, stream>>>(counts, cursor, 20000);
    k_place<<<2344, 256, 0, stream>>>(center, cursor, eidx);
    k_edge <<<768, 512, 0, stream>>>(hE, center, eidx, Pbf, bv1, bv2, bv3,
                                     bb2, bb3, wbf, Vbf, ew, denom);
    k_agg_out<<<5000, 256, 0, stream>>>(Vbf, ew, denom, cursor, counts, woT, out);
}

// Round 2
// 1245.654 us; speedup vs baseline: 1.8342x; 1.8342x over previous
//
#include <hip/hip_runtime.h>
#include <hip/hip_bf16.h>
#include <math.h>

#define TE 32
#define XS 264          // x tile stride (shorts): 256 hE cols + 8 pad
#define HS 264          // hidden tile stride (shorts)
#define NTILES 18750    // 600000 / TE

typedef __attribute__((ext_vector_type(8))) short bf16x8;
typedef __attribute__((ext_vector_type(4))) float f32x4;

__device__ __forceinline__ unsigned short f2b(float f) {
    unsigned int x = __float_as_uint(f);
    unsigned int r = x + 0x7fffu + ((x >> 16) & 1u);   // RTNE
    return (unsigned short)(r >> 16);
}
__device__ __forceinline__ float b2f(unsigned short u) {
    return __uint_as_float(((unsigned int)u) << 16);
}
// Branchless erf-gelu (Abramowitz-Stegun 7.1.26, |erf err| <= 1.5e-7).
__device__ __forceinline__ float gelu_fast(float v) {
    float x = fabsf(v) * 0.70710678118654752f;
    float t = __builtin_amdgcn_rcpf(1.0f + 0.3275911f * x);
    float p = ((((1.061405429f * t - 1.453152027f) * t + 1.421413741f) * t
                - 0.284496736f) * t + 0.254829592f) * t;
    float e = __expf(-x * x);
    float erfp = 1.0f - p * e;                 // erf(|v|/sqrt2) >= 0
    return 0.5f * v * (1.0f + copysignf(erfp, v));
}

// ---------------- weight prep: fp32 -> bf16, Wb3 pad, Wo transpose, Wb1[:, :128]^T fp32 ----------------
// wbf layout (shorts): Wb1[:,128:384] 32768 | Wb2 16384 | Wv1 32768 | Wv2 16384
//                      | Wv3 16384 | Wb3 padded 16x128 = 2048   (total 116736)
__global__ void __launch_bounds__(256)
k_pre(const float* __restrict__ Wb1, const float* __restrict__ Wb2,
      const float* __restrict__ Wv1, const float* __restrict__ Wv2,
      const float* __restrict__ Wv3, const float* __restrict__ Wb3,
      const float* __restrict__ Wo,
      unsigned short* __restrict__ wbf, float* __restrict__ woT,
      float* __restrict__ wb1T) {
    int t = blockIdx.x * 256 + threadIdx.x;
    if (t < 32768) { int f = t >> 8, k = t & 255; wbf[t] = f2b(Wb1[f * 384 + 128 + k]); }
    else if (t < 49152)  wbf[t] = f2b(Wb2[t - 32768]);
    else if (t < 81920)  wbf[t] = f2b(Wv1[t - 49152]);
    else if (t < 98304)  wbf[t] = f2b(Wv2[t - 81920]);
    else if (t < 114688) wbf[t] = f2b(Wv3[t - 98304]);
    else if (t < 116736) {
        int i = t - 114688; int r = i >> 7, k = i & 127;
        wbf[t] = (r < 4) ? f2b(Wb3[r * 128 + k]) : (unsigned short)0;
    } else if (t < 133120) {
        int i = t - 116736; int j = i >> 7, k = i & 127;
        woT[k * 128 + j] = Wo[j * 128 + k];
    } else if (t < 149504) {
        int i = t - 133120; int f = i >> 7, k = i & 127;
        wb1T[k * 128 + f] = Wb1[f * 384 + k];      // cols 0..127, transposed
    }
}

// ---------------- per-node bias-L1 partial: P = h_V @ Wb1[:, :128]^T + bb1 (bf16) ----------------
// coalesced: wb1T rows are 512B contiguous (L2-resident), h_V broadcast from LDS
__global__ void __launch_bounds__(256)
k_pnode(const float* __restrict__ hV, const float* __restrict__ wb1T,
        const float* __restrict__ bb1, unsigned short* __restrict__ Pbf) {
    __shared__ float hvs[4][128];
    const int t = threadIdx.x;
    const int w = t >> 6, lane = t & 63;
    const int node = blockIdx.x * 4 + w;
    {
        int idx = t * 2;                         // 512 floats per block
        *(float2*)&((float*)hvs)[idx] = *(const float2*)(hV + (size_t)blockIdx.x * 512 + idx);
    }
    __syncthreads();
    float a0 = bb1[lane], a1 = bb1[lane + 64];
    #pragma unroll 8
    for (int k = 0; k < 128; ++k) {
        float h = hvs[w][k];
        a0 += h * wb1T[k * 128 + lane];
        a1 += h * wb1T[k * 128 + lane + 64];
    }
    Pbf[(size_t)node * 128 + lane]      = f2b(a0);
    Pbf[(size_t)node * 128 + 64 + lane] = f2b(a1);
}

// ---------------- CSR build ----------------
__global__ void __launch_bounds__(256)
k_hist(const int* __restrict__ center, int* __restrict__ counts) {
    int t = blockIdx.x * 256 + threadIdx.x;
    if (t < 600000) atomicAdd(&counts[center[t]], 1);
}

// single-block shuffle scan: cursor = exclusive prefix of counts
__global__ void __launch_bounds__(1024)
k_scan(const int* __restrict__ counts, int* __restrict__ cursor, int n) {
    __shared__ int wtot[16];
    const int t = threadIdx.x, lane = t & 63, w = t >> 6;
    const int CH = 20;                       // 1024*20 >= 20000
    const int base = t * CH;
    int loc[CH]; int s = 0;
    #pragma unroll
    for (int i = 0; i < CH; ++i) {
        int idx = base + i;
        int v = (idx < n) ? counts[idx] : 0;
        loc[i] = s; s += v;
    }
    int inc = s;
    for (int o = 1; o < 64; o <<= 1) { int u = __shfl_up(inc, o); if (lane >= o) inc += u; }
    if (lane == 63) wtot[w] = inc;
    __syncthreads();
    if (w == 0 && lane < 16) {
        int v = wtot[lane]; int p = v;
        for (int o = 1; o < 16; o <<= 1) { int u = __shfl_up(p, o); if (lane >= o) p += u; }
        wtot[lane] = p - v;                  // exclusive wave offset
    }
    __syncthreads();
    const int excl = wtot[w] + inc - s;
    #pragma unroll
    for (int i = 0; i < CH; ++i) {
        int idx = base + i;
        if (idx < n) cursor[idx] = excl + loc[i];
    }
}

__global__ void __launch_bounds__(256)
k_place(const int* __restrict__ center, int* __restrict__ cursor, int* __restrict__ eidx) {
    int t = blockIdx.x * 256 + threadIdx.x;
    if (t < 600000) {
        int p = atomicAdd(&cursor[center[t]], 1);
        eidx[p] = t;
    }
}

// ---------------- fused per-edge MLPs, edges processed in node-sorted (eidx) order ----------------
#define PREFETCH(eg) { \
    int e0_ = eidx[(eg) + wave];      int e1_ = eidx[(eg) + wave + 8]; \
    int e2_ = eidx[(eg) + wave + 16]; int e3_ = eidx[(eg) + wave + 24]; \
    if (t < 32) pc = center[eidx[(eg) + t]]; \
    pre[0] = *(const float4*)(hE + (size_t)e0_ * 256 + kq4); \
    pre[1] = *(const float4*)(hE + (size_t)e1_ * 256 + kq4); \
    pre[2] = *(const float4*)(hE + (size_t)e2_ * 256 + kq4); \
    pre[3] = *(const float4*)(hE + (size_t)e3_ * 256 + kq4); }

#define STAGE() { \
    _Pragma("unroll") \
    for (int i_ = 0; i_ < 4; ++i_) { \
        ushort4 p_; p_.x = f2b(pre[i_].x); p_.y = f2b(pre[i_].y); \
        p_.z = f2b(pre[i_].z); p_.w = f2b(pre[i_].w); \
        *(ushort4*)&xs[(wave + i_ * 8) * XS + kq4] = p_; } \
    if (t < 32) cs[t] = pc; }

__global__ void __launch_bounds__(512, 2)     // 2 waves/SIMD min: VGPR cap 256, weights stay resident
k_edge(const float* __restrict__ hE, const int* __restrict__ center,
       const int* __restrict__ eidx, const unsigned short* __restrict__ Pbf,
       const float* __restrict__ bv1, const float* __restrict__ bv2,
       const float* __restrict__ bv3, const float* __restrict__ bb2,
       const float* __restrict__ bb3, const unsigned short* __restrict__ wbf,
       unsigned short* __restrict__ Vbf, float* __restrict__ ew, float* __restrict__ denom)
{
    __shared__ unsigned short smem[25344];   // xs[32*264] + h1[32*264] + h2[32*264] = 50688 B
    __shared__ int cs[32];                   // center of each (permuted) edge row
    const int t = threadIdx.x;
    const int wave = t >> 6, lane = t & 63;
    const int c16 = lane & 15, q = lane >> 4;
    const int kq4 = (t & 63) * 4;

    unsigned short* xs = smem;               // [32][XS] bf16(h_E) rows in eidx order
    unsigned short* h1 = smem + 8448;        // [32][HS]
    unsigned short* h2 = smem + 16896;       // [32][HS]

    const unsigned short* Wb1bf = wbf;               // 128 x 256 (cols 128..383 of Wb1)
    const unsigned short* Wb2bf = wbf + 32768;
    const unsigned short* Wv1bf = wbf + 49152;
    const unsigned short* Wv2bf = wbf + 81920;
    const unsigned short* Wv3bf = wbf + 98304;
    const unsigned short* Wb3bf = wbf + 114688;      // 16 x 128 (rows 4..15 zero)

    float4 pre[4]; int pc = 0;
    PREFETCH(blockIdx.x * TE);               // prologue prefetch

    if (wave < 4) {
        // ================= bias path: features fb..fb+31 =================
        const int fb = wave * 32;
        bf16x8 wb1r[2][8], wb2r[2][4], wb3f[4];
        float bias2[2]; float bb3c = 0.f;
        #pragma unroll
        for (int nt = 0; nt < 2; ++nt) {
            const int fr = fb + nt * 16 + c16;
            #pragma unroll
            for (int ks = 0; ks < 8; ++ks)
                wb1r[nt][ks] = *(const bf16x8*)(Wb1bf + (size_t)fr * 256 + ks * 32 + q * 8);
            #pragma unroll
            for (int ks = 0; ks < 4; ++ks)
                wb2r[nt][ks] = *(const bf16x8*)(Wb2bf + (size_t)fr * 128 + ks * 32 + q * 8);
            bias2[nt] = bb2[fr];
        }
        if (wave == 0) {
            #pragma unroll
            for (int ks = 0; ks < 4; ++ks)
                wb3f[ks] = *(const bf16x8*)(Wb3bf + (size_t)c16 * 128 + ks * 32 + q * 8);
            bb3c = bb3[c16 & 3];
        }
        for (int tile = blockIdx.x; tile < NTILES; tile += gridDim.x) {
            const int eg0 = tile * TE;
            STAGE();
            int nxt = tile + gridDim.x;
            if (nxt < NTILES) PREFETCH(nxt * TE);
            __syncthreads();
            // ---- per-row gather of precomputed h_V partial (sorted centers -> cache-hot) ----
            float pva[2][2][4];
            #pragma unroll
            for (int m = 0; m < 2; ++m)
                #pragma unroll
                for (int r = 0; r < 4; ++r) {
                    int c = cs[m * 16 + q * 4 + r];
                    pva[m][0][r] = b2f(Pbf[(size_t)c * 128 + fb + c16]);
                    pva[m][1][r] = b2f(Pbf[(size_t)c * 128 + fb + 16 + c16]);
                }
            // ---- L1: h1b = gelu(hE @ Wb1[:,128:]^T + P[center]), K=256 ----
            #pragma unroll
            for (int m = 0; m < 2; ++m) {
                bf16x8 af[8];
                #pragma unroll
                for (int ks = 0; ks < 8; ++ks)
                    af[ks] = *(const bf16x8*)&xs[(m * 16 + c16) * XS + ks * 32 + q * 8];
                f32x4 a0 = {0.f,0.f,0.f,0.f}, a1 = {0.f,0.f,0.f,0.f};
                #pragma unroll
                for (int ks = 0; ks < 8; ++ks) {
                    a0 = __builtin_amdgcn_mfma_f32_16x16x32_bf16(af[ks], wb1r[0][ks], a0, 0, 0, 0);
                    a1 = __builtin_amdgcn_mfma_f32_16x16x32_bf16(af[ks], wb1r[1][ks], a1, 0, 0, 0);
                }
                #pragma unroll
                for (int r = 0; r < 4; ++r) {
                    int row = (m * 16 + q * 4 + r) * HS;
                    h1[row + fb + c16]      = f2b(gelu_fast(a0[r] + pva[m][0][r]));
                    h1[row + fb + 16 + c16] = f2b(gelu_fast(a1[r] + pva[m][1][r]));
                }
            }
            __syncthreads();
            // ---- L2: h2b = gelu(h1b @ Wb2^T + bb2), K=128 ----
            #pragma unroll
            for (int m = 0; m < 2; ++m) {
                bf16x8 ah[4];
                #pragma unroll
                for (int ks = 0; ks < 4; ++ks)
                    ah[ks] = *(const bf16x8*)&h1[(m * 16 + c16) * HS + ks * 32 + q * 8];
                f32x4 a0 = {0.f,0.f,0.f,0.f}, a1 = {0.f,0.f,0.f,0.f};
                #pragma unroll
                for (int ks = 0; ks < 4; ++ks) {
                    a0 = __builtin_amdgcn_mfma_f32_16x16x32_bf16(ah[ks], wb2r[0][ks], a0, 0, 0, 0);
                    a1 = __builtin_amdgcn_mfma_f32_16x16x32_bf16(ah[ks], wb2r[1][ks], a1, 0, 0, 0);
                }
                #pragma unroll
                for (int r = 0; r < 4; ++r) {
                    int row = (m * 16 + q * 4 + r) * HS;
                    h2[row + fb + c16]      = f2b(gelu_fast(a0[r] + bias2[0]));
                    h2[row + fb + 16 + c16] = f2b(gelu_fast(a1[r] + bias2[1]));
                }
            }
            __syncthreads();
            // ---- L3 (wave 0, MFMA): logits = h2b @ Wb3pad^T -> ew (contiguous), denom atomics ----
            if (wave == 0) {
                #pragma unroll
                for (int m = 0; m < 2; ++m) {
                    bf16x8 ah[4];
                    #pragma unroll
                    for (int ks = 0; ks < 4; ++ks)
                        ah[ks] = *(const bf16x8*)&h2[(m * 16 + c16) * HS + ks * 32 + q * 8];
                    f32x4 a = {0.f,0.f,0.f,0.f};
                    #pragma unroll
                    for (int ks = 0; ks < 4; ++ks)
                        a = __builtin_amdgcn_mfma_f32_16x16x32_bf16(ah[ks], wb3f[ks], a, 0, 0, 0);
                    if (c16 < 4) {
                        #pragma unroll
                        for (int r = 0; r < 4; ++r) {
                            int row = m * 16 + q * 4 + r;
                            float wv = (a[r] + bb3c) * 0.17677669529663689f;  // 1/sqrt(32)
                            float evx = __expf(wv);                 // |w| small: no max-sub
                            ew[(size_t)(eg0 + row) * 4 + c16] = evx;
                            atomicAdd(&denom[(size_t)cs[row] * 4 + c16], evx);
                        }
                    }
                }
            }
        }
    } else {
        // ================= value path: features fv..fv+31 =================
        const int fv = (wave - 4) * 32;
        bf16x8 wv1r[2][8], wv2r[2][4], wv3r[2][4];
        float b1[2], b2[2], b3[2];
        #pragma unroll
        for (int nt = 0; nt < 2; ++nt) {
            const int fr = fv + nt * 16 + c16;
            #pragma unroll
            for (int ks = 0; ks < 8; ++ks)
                wv1r[nt][ks] = *(const bf16x8*)(Wv1bf + (size_t)fr * 256 + ks * 32 + q * 8);
            #pragma unroll
            for (int ks = 0; ks < 4; ++ks) {
                wv2r[nt][ks] = *(const bf16x8*)(Wv2bf + (size_t)fr * 128 + ks * 32 + q * 8);
                wv3r[nt][ks] = *(const bf16x8*)(Wv3bf + (size_t)fr * 128 + ks * 32 + q * 8);
            }
            b1[nt] = bv1[fr]; b2[nt] = bv2[fr]; b3[nt] = bv3[fr];
        }
        for (int tile = blockIdx.x; tile < NTILES; tile += gridDim.x) {
            const int eg0 = tile * TE;
            STAGE();
            int nxt = tile + gridDim.x;
            if (nxt < NTILES) PREFETCH(nxt * TE);
            __syncthreads();
            // ---- L1: v1 = gelu(h_E @ Wv1^T + bv1), K=256 ----
            #pragma unroll
            for (int m = 0; m < 2; ++m) {
                bf16x8 af[8];
                #pragma unroll
                for (int ks = 0; ks < 8; ++ks)
                    af[ks] = *(const bf16x8*)&xs[(m * 16 + c16) * XS + ks * 32 + q * 8];
                f32x4 a0 = {0.f,0.f,0.f,0.f}, a1 = {0.f,0.f,0.f,0.f};
                #pragma unroll
                for (int ks = 0; ks < 8; ++ks) {
                    a0 = __builtin_amdgcn_mfma_f32_16x16x32_bf16(af[ks], wv1r[0][ks], a0, 0, 0, 0);
                    a1 = __builtin_amdgcn_mfma_f32_16x16x32_bf16(af[ks], wv1r[1][ks], a1, 0, 0, 0);
                }
                #pragma unroll
                for (int r = 0; r < 4; ++r) {
                    int row = (m * 16 + q * 4 + r) * HS;
                    h1[row + 128 + fv + c16]      = f2b(gelu_fast(a0[r] + b1[0]));
                    h1[row + 128 + fv + 16 + c16] = f2b(gelu_fast(a1[r] + b1[1]));
                }
            }
            __syncthreads();
            // ---- L2: v2 = gelu(v1 @ Wv2^T + bv2), K=128 ----
            #pragma unroll
            for (int m = 0; m < 2; ++m) {
                bf16x8 ah[4];
                #pragma unroll
                for (int ks = 0; ks < 4; ++ks)
                    ah[ks] = *(const bf16x8*)&h1[(m * 16 + c16) * HS + 128 + ks * 32 + q * 8];
                f32x4 a0 = {0.f,0.f,0.f,0.f}, a1 = {0.f,0.f,0.f,0.f};
                #pragma unroll
                for (int ks = 0; ks < 4; ++ks) {
                    a0 = __builtin_amdgcn_mfma_f32_16x16x32_bf16(ah[ks], wv2r[0][ks], a0, 0, 0, 0);
                    a1 = __builtin_amdgcn_mfma_f32_16x16x32_bf16(ah[ks], wv2r[1][ks], a1, 0, 0, 0);
                }
                #pragma unroll
                for (int r = 0; r < 4; ++r) {
                    int row = (m * 16 + q * 4 + r) * HS;
                    h2[row + 128 + fv + c16]      = f2b(gelu_fast(a0[r] + b2[0]));
                    h2[row + 128 + fv + 16 + c16] = f2b(gelu_fast(a1[r] + b2[1]));
                }
            }
            __syncthreads();
            // ---- L3: V = v2 @ Wv3^T + bv3 -> Vbf at CONTIGUOUS (sorted) position ----
            #pragma unroll
            for (int m = 0; m < 2; ++m) {
                bf16x8 av[4];
                #pragma unroll
                for (int ks = 0; ks < 4; ++ks)
                    av[ks] = *(const bf16x8*)&h2[(m * 16 + c16) * HS + 128 + ks * 32 + q * 8];
                f32x4 a0 = {0.f,0.f,0.f,0.f}, a1 = {0.f,0.f,0.f,0.f};
                #pragma unroll
                for (int ks = 0; ks < 4; ++ks) {
                    a0 = __builtin_amdgcn_mfma_f32_16x16x32_bf16(av[ks], wv3r[0][ks], a0, 0, 0, 0);
                    a1 = __builtin_amdgcn_mfma_f32_16x16x32_bf16(av[ks], wv3r[1][ks], a1, 0, 0, 0);
                }
                #pragma unroll
                for (int r = 0; r < 4; ++r) {
                    size_t row = (size_t)(eg0 + m * 16 + q * 4 + r) * 128;
                    Vbf[row + fv + c16]      = f2b(a0[r] + b3[0]);
                    Vbf[row + fv + 16 + c16] = f2b(a1[r] + b3[1]);
                }
            }
        }
    }
}

// -------- gather+output: Vbf/ew CONTIGUOUS per node -> pure streaming --------
__global__ void __launch_bounds__(256)
k_agg_out(const unsigned short* __restrict__ Vbf, const float* __restrict__ ew,
          const float* __restrict__ denom, const int* __restrict__ cursor,
          const int* __restrict__ counts, const float* __restrict__ woT,
          float* __restrict__ out)
{
    __shared__ float aggs[4][128];
    const int t = threadIdx.x;
    const int ln = t >> 6;
    const int node = blockIdx.x * 4 + ln;
    const int lane = t & 63;
    const int j = lane * 2, head = j >> 5;
    {
        int deg = counts[node];
        int off = cursor[node] - deg;        // cursor(after place) = start + deg
        float den = denom[(size_t)node * 4 + head];
        float dinv = (den != 0.f) ? (1.f / den) : 0.f;
        const unsigned short* vp = Vbf + (size_t)off * 128 + j;
        const float* ep = ew + (size_t)off * 4 + head;
        float a0 = 0.f, a1 = 0.f;
        for (int i = 0; i < deg; ++i) {
            float at = ep[(size_t)i * 4] * dinv;
            ushort2 v = *(const ushort2*)(vp + (size_t)i * 128);
            a0 += at * b2f(v.x);
            a1 += at * b2f(v.y);
        }
        aggs[ln][j]     = a0;
        aggs[ln][j + 1] = a1;
    }
    __syncthreads();
    {
        const int c = t & 127, nh = t >> 7;
        float o0 = 0.f, o1 = 0.f;
        for (int k = 0; k < 128; ++k) {
            float w = woT[k * 128 + c];
            o0 += w * aggs[nh][k];
            o1 += w * aggs[nh + 2][k];
        }
        out[(size_t)(blockIdx.x * 4 + nh) * 128 + c]     = o0;
        out[(size_t)(blockIdx.x * 4 + nh + 2) * 128 + c] = o1;
    }
}

extern "C" void kernel_launch(void* const* d_in, const int* in_sizes, int n_in,
                              void* d_out, int out_size, void* d_ws, size_t ws_size,
                              hipStream_t stream) {
    const float* hV  = (const float*)d_in[0];
    const float* hE  = (const float*)d_in[1];
    const float* Wv1 = (const float*)d_in[2];
    const float* bv1 = (const float*)d_in[3];
    const float* Wv2 = (const float*)d_in[4];
    const float* bv2 = (const float*)d_in[5];
    const float* Wv3 = (const float*)d_in[6];
    const float* bv3 = (const float*)d_in[7];
    const float* Wb1 = (const float*)d_in[8];
    const float* bb1 = (const float*)d_in[9];
    const float* Wb2 = (const float*)d_in[10];
    const float* bb2 = (const float*)d_in[11];
    const float* Wb3 = (const float*)d_in[12];
    const float* bb3 = (const float*)d_in[13];
    const float* Wo  = (const float*)d_in[14];
    const int* center = (const int*)d_in[15];
    float* out = (float*)d_out;

    // ---- workspace layout (peak 171,564,544 B < proven 174 MB) ----
    char* ws = (char*)d_ws;
    unsigned short* wbf = (unsigned short*)(ws + 0);          // 116736 bf16 (233472 B)
    float* woT     = (float*)(ws + 233472);                   // 16384 f32   (65536 B)
    float* wb1T    = (float*)(ws + 299008);                   // 16384 f32   (65536 B)
    unsigned short* Pbf = (unsigned short*)(ws + 364544);     // 2.56M bf16  (5120000 B)
    float* denom   = (float*)(ws + 5484544);                  // 80000 f32   (320000 B)
    int*   counts  = (int*)  (ws + 5804544);                  // 20000       (80000 B)
    int*   cursor  = (int*)  (ws + 5884544);                  // 20000       (80000 B)
    int*   eidx    = (int*)  (ws + 5964544);                  // 600000      (2400000 B)
    float* ew      = (float*)(ws + 8364544);                  // 2400000 f32 (9600000 B)
    unsigned short* Vbf = (unsigned short*)(ws + 17964544);   // 76800000 bf16 (153600000 B)

    hipMemsetAsync(ws + 5484544, 0, 400000, stream);          // zero denom + counts
    k_pre  <<<584, 256, 0, stream>>>(Wb1, Wb2, Wv1, Wv2, Wv3, Wb3, Wo, wbf, woT, wb1T);
    k_pnode<<<5000, 256, 0, stream>>>(hV, wb1T, bb1, Pbf);
    k_hist <<<2344, 256, 0, stream>>>(center, counts);
    k_scan <<<1, 1024, 0, stream>>>(counts, cursor, 20000);
    k_place<<<2344, 256, 0, stream>>>(center, cursor, eidx);
    k_edge <<<512, 512, 0, stream>>>(hE, center, eidx, Pbf, bv1, bv2, bv3,
                                     bb2, bb3, wbf, Vbf, ew, denom);
    k_agg_out<<<5000, 256, 0, stream>>>(Vbf, ew, denom, cursor, counts, woT, out);
}